// Round 9
// baseline (138.605 us; speedup 1.0000x reference)
//
#include <hip/hip_runtime.h>

#define B_ 2
#define L_ 256
#define D_ 512
#define H_ 8
#define DV_ 64
#define NEGINF 1e12f

// ws layout (float offsets):
#define WS_VALUE 0          // [B*H][L][DV]  = 262144
#define WS_WR    262144     // [512][8]      = 4096
#define WS_SSRC  266240     // [B*H][L]      = 4096
#define WS_STGT  270336     // [B*H][L]      = 4096

#define GLOAD_LDS16(g, l)                                                     \
    __builtin_amdgcn_global_load_lds(                                         \
        (const __attribute__((address_space(1))) void*)(g),                   \
        (__attribute__((address_space(3))) void*)(l), 16, 0, 0)

// ---------------- Kernel A: WR[k][h] = sum_d W_relation[k][h*64+d] * w_rel[h][d]
__global__ __launch_bounds__(256) void k_wr(const float* __restrict__ Wrel,
                                            const float* __restrict__ wrel,
                                            float* __restrict__ WR) {
    int flat = blockIdx.x * 256 + threadIdx.x;   // 4096 = 512*8
    int k = flat >> 3, h = flat & 7;
    const float* a = Wrel + k * 512 + h * 64;
    const float* b = wrel + h * 64;
    float s = 0.f;
#pragma unroll
    for (int d = 0; d < 64; d += 4) {
        float4 x = *(const float4*)(a + d);
        float4 y = *(const float4*)(b + d);
        s += x.x * y.x + x.y * y.y + x.z * y.z + x.w * y.w;
    }
    WR[k * 8 + h] = s;
}

// ---------------- Kernel B: value = inp @ W_value, + fused s_src/s_tgt epilogue
__global__ __launch_bounds__(256) void k_value(const float* __restrict__ inp,
                                               const float* __restrict__ Wv,
                                               const float* __restrict__ wsrc,
                                               const float* __restrict__ wtgt,
                                               float* __restrict__ value,
                                               float* __restrict__ s_src,
                                               float* __restrict__ s_tgt) {
    int blk = blockIdx.x;          // 256 blocks = 128 row-tiles x 2 col-halves
    int ct  = blk & 1;
    int rt  = blk >> 1;
    int n   = ct * 256 + threadIdx.x;   // output col 0..511
    int r0  = rt * 4;
    const float* i0 = inp + (size_t)(r0 + 0) * 512;
    const float* i1 = inp + (size_t)(r0 + 1) * 512;
    const float* i2 = inp + (size_t)(r0 + 2) * 512;
    const float* i3 = inp + (size_t)(r0 + 3) * 512;
    float a0 = 0.f, a1 = 0.f, a2 = 0.f, a3 = 0.f;
#pragma unroll 16
    for (int k = 0; k < 512; ++k) {
        float w = Wv[(size_t)k * 512 + n];
        a0 = fmaf(i0[k], w, a0);
        a1 = fmaf(i1[k], w, a1);
        a2 = fmaf(i2[k], w, a2);
        a3 = fmaf(i3[k], w, a3);
    }
    int h = n >> 6, dv = n & 63;
    float acc[4] = {a0, a1, a2, a3};
    float wsv = wsrc[h * 64 + dv];
    float wtv = wtgt[h * 64 + dv];
#pragma unroll
    for (int r = 0; r < 4; ++r) {
        int row = r0 + r;
        int b = row >> 8, l = row & 255;
        value[(((size_t)(b * 8 + h)) * 256 + l) * 64 + dv] = acc[r];
        float ss = acc[r] * wsv;
        float st = acc[r] * wtv;
#pragma unroll
        for (int off = 32; off >= 1; off >>= 1) {
            ss += __shfl_xor(ss, off);
            st += __shfl_xor(st, off);
        }
        if (dv == 0) {
            s_src[(size_t)(b * 8 + h) * 256 + l] = ss;
            s_tgt[(size_t)(b * 8 + h) * 256 + l] = st;
        }
    }
}

// ---------------- Kernel D: fused s_rel + softmax + out, PRODUCER/CONSUMER.
// Block = one (b,i), 320 threads = 4 consumer waves (thread t owns row t) +
// 1 producer wave (issues global_load_lds only, never computes).
// Ring: 4 slots x 16KB (tile = 256 rows x 16 floats). Producer throttled by
// counted vmcnt(32) (2 tiles in flight) + done[] slot recycling; consumers
// poll ready[], consume, bump done[]. No __syncthreads in the pipeline.
__global__ __launch_bounds__(320, 2) void k_main(const float* __restrict__ rel,    // [bi][j][k]
                                                 const int*   __restrict__ mask,   // [bi][j]
                                                 const float* __restrict__ adj,    // [b][h][i][j]
                                                 const float* __restrict__ inp,    // [bi][D]
                                                 const float* __restrict__ value,  // [b][h][j][dv]
                                                 const float* __restrict__ WR,     // [k][h]
                                                 const float* __restrict__ s_src,  // [b][h][j]
                                                 const float* __restrict__ s_tgt,  // [b][h][i]
                                                 float* __restrict__ out) {        // [bi][D]
    __shared__ float ring[16384];      // 4 x 4096 floats (16KB slots)
    __shared__ int ready_s[32];
    __shared__ int done_s[32];
    int bi   = blockIdx.x;
    int b    = bi >> 8;
    int i    = bi & 255;
    int tid  = threadIdx.x;
    int lane = tid & 63;
    int wv   = tid >> 6;

    const float* relbase = rel + (size_t)bi * 256 * 512;

    if (tid < 32) { ready_s[tid] = 0; done_s[tid] = 0; }
    __syncthreads();

    float acc[8];
#pragma unroll
    for (int h = 0; h < 8; ++h) acc[h] = 0.f;

    if (wv == 4) {
        // ---------------- PRODUCER ----------------
        // instr ii covers rows ii*16 + (lane>>2), 64B chunk (lane&3) of the
        // tile's 64B row-slice; dst is wave-uniform (HW adds lane*16).
        const float* src0 = relbase + (size_t)(lane >> 2) * 512 + (lane & 3) * 4;
        for (int t = 0; t < 32; ++t) {
            if (t >= 4) {
                while (__hip_atomic_load(&done_s[t - 4], __ATOMIC_ACQUIRE,
                                         __HIP_MEMORY_SCOPE_WORKGROUP) < 4)
                    __builtin_amdgcn_s_sleep(2);
            }
            const float* s = src0 + t * 16;
            float* dst = &ring[(t & 3) * 4096];
#pragma unroll
            for (int ii = 0; ii < 16; ++ii)
                GLOAD_LDS16(s + (size_t)ii * 16 * 512, dst + ii * 256);
            if (t >= 2) {
                asm volatile("s_waitcnt vmcnt(32)" ::: "memory");
                if (lane == 0)
                    __hip_atomic_store(&ready_s[t - 2], 1, __ATOMIC_RELEASE,
                                       __HIP_MEMORY_SCOPE_WORKGROUP);
            }
        }
        asm volatile("s_waitcnt vmcnt(16)" ::: "memory");
        if (lane == 0)
            __hip_atomic_store(&ready_s[30], 1, __ATOMIC_RELEASE,
                               __HIP_MEMORY_SCOPE_WORKGROUP);
        asm volatile("s_waitcnt vmcnt(0)" ::: "memory");
        if (lane == 0)
            __hip_atomic_store(&ready_s[31], 1, __ATOMIC_RELEASE,
                               __HIP_MEMORY_SCOPE_WORKGROUP);
    } else {
        // ---------------- CONSUMERS ----------------
        for (int t = 0; t < 32; ++t) {
            while (__hip_atomic_load(&ready_s[t], __ATOMIC_ACQUIRE,
                                     __HIP_MEMORY_SCOPE_WORKGROUP) == 0)
                __builtin_amdgcn_s_sleep(2);
            const float* myrow = &ring[(t & 3) * 4096 + tid * 16];
            const float* wrt   = WR + t * 128;   // wave-uniform -> scalar
#pragma unroll
            for (int q = 0; q < 4; ++q) {
                float4 x = *(const float4*)(myrow + q * 4);
#pragma unroll
                for (int h = 0; h < 8; ++h) {
                    acc[h] = fmaf(x.x, wrt[(q * 4 + 0) * 8 + h],
                             fmaf(x.y, wrt[(q * 4 + 1) * 8 + h],
                             fmaf(x.z, wrt[(q * 4 + 2) * 8 + h],
                             fmaf(x.w, wrt[(q * 4 + 3) * 8 + h], acc[h]))));
                }
            }
            asm volatile("s_waitcnt lgkmcnt(0)" ::: "memory");
            if (lane == 0)
                __hip_atomic_fetch_add(&done_s[t], 1, __ATOMIC_RELEASE,
                                       __HIP_MEMORY_SCOPE_WORKGROUP);
        }
    }

    __syncthreads();
    // publish srel into ring slot 0 (all tiles consumed; slot 0 free)
    float* srel_s = ring;              // [h][j]  (2048 floats)
    float* attn_s = ring + 2048;       // [h][j]  (2048 floats)
    if (tid < 256) {
#pragma unroll
        for (int h = 0; h < 8; ++h) srel_s[h * 256 + tid] = acc[h];
    }
    __syncthreads();

    // ---- Phase 2: per-h row softmax over j; 32 lanes per h, 8 j per lane
    if (tid < 256) {
        int h  = tid >> 5;
        int ln = tid & 31;
        float stgt = s_tgt[(size_t)(b * 8 + h) * 256 + i];
        const float* ssrc   = s_src + (size_t)(b * 8 + h) * 256;
        const float* adjrow = adj + ((size_t)(b * 8 + h) * 256 + i) * 256;
        const int*   mrow   = mask + (size_t)bi * 256;

        float sc[8], av[8];
        int mb = 0;
        float rowmax = -3.0e38f;
#pragma unroll
        for (int t = 0; t < 8; ++t) {
            int j = ln + 32 * t;
            float a = adjrow[j];
            av[t] = a;
            int m = mrow[j];
            float s = ssrc[j] + stgt + srel_s[h * 256 + j];
            s = (s >= 0.f) ? s : 0.2f * s;     // leaky relu
            if (m != 0) { s = -NEGINF; mb |= (1 << t); }
            if (a == 0.f) s = -NEGINF;
            sc[t] = s;
            rowmax = fmaxf(rowmax, s);
        }
#pragma unroll
        for (int off = 16; off >= 1; off >>= 1)
            rowmax = fmaxf(rowmax, __shfl_xor(rowmax, off));

        float rowsum = 0.f;
#pragma unroll
        for (int t = 0; t < 8; ++t) {
            sc[t] = expf(sc[t] - rowmax);
            rowsum += sc[t];
        }
#pragma unroll
        for (int off = 16; off >= 1; off >>= 1)
            rowsum += __shfl_xor(rowsum, off);
        float rinv = 1.0f / rowsum;

        float sumabs = 0.f;
#pragma unroll
        for (int t = 0; t < 8; ++t) {
            float p = sc[t] * rinv;
            float invv = (av[t] == 0.f) ? 1e-12f : (1.0f / av[t]);
            p *= invv;
            sc[t] = p;
            sumabs += fabsf(p);
        }
#pragma unroll
        for (int off = 16; off >= 1; off >>= 1)
            sumabs += __shfl_xor(sumabs, off);

        float rdn = 1.0f / fmaxf(sumabs, 1e-12f);
#pragma unroll
        for (int t = 0; t < 8; ++t) {
            float p = sc[t] * rdn;
            if (mb & (1 << t)) p = 0.f;
            if (av[t] == 0.f) p = 0.f;
            attn_s[h * 256 + ln + 32 * t] = p;
        }
    }
    __syncthreads();

    // ---- Phase 3: out[bi][h*64+d] = inp + sum_j attn[h][j] * value[b][h][j][d]
    if (tid < 256) {
        int h  = tid >> 5;
        int d0 = (tid & 31) * 2;
        const float* vbase = value + ((size_t)(b * 8 + h) * 256) * 64 + d0;
        const float* arow  = attn_s + h * 256;
        float ax = 0.f, ay = 0.f;
#pragma unroll 8
        for (int j = 0; j < 256; ++j) {
            float a = arow[j];
            float2 v2 = *(const float2*)(vbase + (size_t)j * 64);
            ax = fmaf(a, v2.x, ax);
            ay = fmaf(a, v2.y, ay);
        }
        size_t o = (size_t)bi * 512 + h * 64 + d0;
        out[o]     = inp[o] + ax;
        out[o + 1] = inp[o + 1] + ay;
    }
}

extern "C" void kernel_launch(void* const* d_in, const int* in_sizes, int n_in,
                              void* d_out, int out_size, void* d_ws, size_t ws_size,
                              hipStream_t stream) {
    const float* inp      = (const float*)d_in[0];
    const float* rel      = (const float*)d_in[1];
    const int*   mask     = (const int*)  d_in[2];
    const float* adj      = (const float*)d_in[3];
    const float* W_value  = (const float*)d_in[4];
    const float* W_rel    = (const float*)d_in[5];
    const float* w_src    = (const float*)d_in[6];
    const float* w_tgt    = (const float*)d_in[7];
    const float* w_rel    = (const float*)d_in[8];
    float* out = (float*)d_out;

    float* ws    = (float*)d_ws;
    float* value = ws + WS_VALUE;
    float* WR    = ws + WS_WR;
    float* s_src = ws + WS_SSRC;
    float* s_tgt = ws + WS_STGT;

    k_wr<<<16, 256, 0, stream>>>(W_rel, w_rel, WR);
    k_value<<<256, 256, 0, stream>>>(inp, W_value, w_src, w_tgt,
                                     value, s_src, s_tgt);
    k_main<<<B_ * L_, 320, 0, stream>>>(rel, mask, adj, inp, value, WR,
                                        s_src, s_tgt, out);
}